// Round 6
// baseline (1015.687 us; speedup 1.0000x reference)
//
#include <hip/hip_runtime.h>

typedef __bf16 bf16x8 __attribute__((ext_vector_type(8)));
typedef float floatx4 __attribute__((ext_vector_type(4)));
typedef unsigned short u16;
typedef unsigned int u32;

__device__ __forceinline__ u16 f2bf(float f) {
    union { float f; unsigned int u; } q; q.f = f;
    unsigned int r = q.u + 0x7FFFu + ((q.u >> 16) & 1u);
    return (u16)(r >> 16);
}
__device__ __forceinline__ float bf2f(u16 b) {
    union { unsigned int u; float f; } q; q.u = ((unsigned int)b) << 16;
    return q.f;
}

// ---------------- fused prep: pack both 3x3 weights, cast wh1, bn params ----------------
__global__ __launch_bounds__(256) void prep(
    const float* __restrict__ wk, const float* __restrict__ wsw, const float* __restrict__ wh1,
    const float* __restrict__ gk, const float* __restrict__ bk,
    const float* __restrict__ mk, const float* __restrict__ vk,
    const float* __restrict__ gs, const float* __restrict__ bs,
    const float* __restrict__ ms, const float* __restrict__ vs,
    const float* __restrict__ gh, const float* __restrict__ bh,
    const float* __restrict__ mh, const float* __restrict__ vh,
    u16* __restrict__ WKP, u16* __restrict__ WSP, u16* __restrict__ WH1P,
    float* __restrict__ par)
{
    int blk = blockIdx.x;
    int t = threadIdx.x;
    if (blk < 4608) {  // pack3x3: OIHW fp32 -> [o][(r*3+c)*256+ci] bf16
        const float* w = (blk < 2304) ? wk : wsw;
        u16* o_ = (blk < 2304) ? WKP : WSP;
        int tid = ((blk < 2304) ? blk : blk - 2304) * 256 + t;
        int o  = tid / 2304;
        int k  = tid - o * 2304;
        int rc = k >> 8;
        int ci = k & 255;
        o_[tid] = f2bf(w[o * 2304 + ci * 9 + rc]);
    } else if (blk < 4864) {  // cast wh1
        int tid = (blk - 4608) * 256 + t;
        WH1P[tid] = f2bf(wh1[tid]);
    } else {  // bn params
        int i = t;
        float s;
        s = gk[i] * rsqrtf(vk[i] + 1e-5f); par[0*256+i] = s; par[1*256+i] = bk[i] - mk[i]*s;
        s = gs[i] * rsqrtf(vs[i] + 1e-5f); par[2*256+i] = s; par[3*256+i] = bs[i] - ms[i]*s;
        s = gh[i] * rsqrtf(vh[i] + 1e-5f); par[4*256+i] = s; par[5*256+i] = bh[i] - mh[i]*s;
    }
}

// ---------------- NCHW fp32 -> NHWC bf16 (both inputs, one launch) ----------------
__global__ __launch_bounds__(256) void nchw2nhwc_t(const float* __restrict__ kin, const float* __restrict__ sin_,
                                                   u16* __restrict__ KIN, u16* __restrict__ SIN) {
    __shared__ float tile[64][33];
    int bid = blockIdx.x;
    const float* in; u16* out; int HW, sptiles;
    if (bid < 1024) { in = kin;  out = KIN; HW = 49;  sptiles = 2;  }
    else            { bid -= 1024; in = sin_; out = SIN; HW = 961; sptiles = 31; }
    int st  = bid % sptiles;
    int tmp = bid / sptiles;
    int ct  = tmp & 3;
    int b   = tmp >> 2;
    int sp0 = st * 32, ci0 = ct * 64;
    int t = threadIdx.x;
    int j = t & 31, i8 = t >> 5;
    const float* ip = in + ((size_t)b * 256 + ci0 + i8) * HW + sp0 + j;
#pragma unroll
    for (int k = 0; k < 8; ++k) {
        if (sp0 + j < HW) tile[i8 + k * 8][j] = ip[(size_t)(k * 8) * HW];
    }
    __syncthreads();
    int cl = t & 63, s4 = t >> 6;
#pragma unroll
    for (int k = 0; k < 8; ++k) {
        int spl = s4 + k * 4;
        int sp  = sp0 + spl;
        if (sp < HW) out[((size_t)b * HW + sp) * 256 + ci0 + cl] = f2bf(tile[cl][spl]);
    }
}

// ---------------- conv as implicit GEMM: register-direct, no LDS, no barriers ----------------
// Each wave owns a 64x64 output tile (4x4 grid of 16x16x32 bf16 MFMA). A/B fragments are
// loaded straight from global into VGPRs: lane (quad,lrow) loads its exact fragment 16B
// (A[m=lrow][k=quad*8+j] from NHWC rows; B[n=lrow][k=quad*8+j] from packed [n][k] weights).
// No global_load_lds -> compiler emits precise vmcnt(N) per use and interleaves the 64 loads
// of a tap with its 128 MFMAs (the AITER-style overlap the barrier+DMA pipeline could not
// express). L2 absorbs the 2x wave-pair re-reads; XCD remap keeps HBM fetch at ~input size.
template<int TAG>
__global__ __launch_bounds__(256, 4) void conv_gemm(
    const u16* __restrict__ Ain, const u16* __restrict__ Wpk,
    const float* __restrict__ scale, const float* __restrict__ shift,
    u16* __restrict__ Out,
    int OHW, int OW, int IW, int bstride, int KW, int nrc, int mblocks)
{
    // XCD-contiguous remap (round-robin lid%8->XCD becomes contiguous m-ranges per XCD)
    const int tot = mblocks * 2;
    const int grp = (tot >> 3) << 3;
    const int lid = blockIdx.x;
    const int nid = (lid < grp) ? ((lid & 7) * (grp >> 3) + (lid >> 3)) : lid;
    const int m0 = (nid >> 1) * 128;
    const int n0 = (nid & 1) * 128;

    const int t    = threadIdx.x;
    const int wave = t >> 6;
    const int lane = t & 63;
    const int quad = lane >> 4;
    const int lrow = lane & 15;
    const int wr   = (wave >> 1) << 6;   // wave 2x2 tiling: A rows shared by wave pairs
    const int wc   = (wave & 1) << 6;

    // per-lane A row pointers (mi = 0..3), at this lane's k-slot (quad*8 elems)
    const u16* ag[4];
#pragma unroll
    for (int mi = 0; mi < 4; ++mi) {
        int m = m0 + wr + mi * 16 + lrow;
        int b = m / OHW; int rem = m - b * OHW; int y = rem / OW; int x = rem - y * OW;
        ag[mi] = Ain + (size_t)b * bstride + (size_t)(y * IW + x) * 256 + (quad << 3);
    }
    const int Ktot = nrc << 8;
    const u16* bp[4];
#pragma unroll
    for (int ni = 0; ni < 4; ++ni)
        bp[ni] = Wpk + (size_t)(n0 + wc + ni * 16 + lrow) * Ktot + (quad << 3);

    floatx4 zero = {0.f, 0.f, 0.f, 0.f};
    floatx4 acc[4][4];
#pragma unroll
    for (int i = 0; i < 4; ++i)
#pragma unroll
        for (int j = 0; j < 4; ++j) acc[i][j] = zero;

    for (int rc = 0; rc < nrc; ++rc) {
        int rr = rc / KW, cc = rc - rr * KW;
        int toff = (rr * IW + cc) << 8;              // tap shift in elements
        const u16* ap[4];
#pragma unroll
        for (int mi = 0; mi < 4; ++mi) ap[mi] = ag[mi] + toff;
#pragma unroll
        for (int ch = 0; ch < 8; ++ch) {             // ci chunk: imm offset ch*64B (<4KB)
            bf16x8 af[4], bfr[4];
#pragma unroll
            for (int mi = 0; mi < 4; ++mi) af[mi]  = *(const bf16x8*)(ap[mi] + (ch << 5));
#pragma unroll
            for (int ni = 0; ni < 4; ++ni) bfr[ni] = *(const bf16x8*)(bp[ni] + (ch << 5));
#pragma unroll
            for (int mi = 0; mi < 4; ++mi)
#pragma unroll
                for (int ni = 0; ni < 4; ++ni)
                    acc[mi][ni] = __builtin_amdgcn_mfma_f32_16x16x32_bf16(af[mi], bfr[ni], acc[mi][ni], 0, 0, 0);
        }
#pragma unroll
        for (int ni = 0; ni < 4; ++ni) bp[ni] += 256;   // next tap's k-range in the weight row
    }

    float sc[4], sh[4];
#pragma unroll
    for (int ni = 0; ni < 4; ++ni) {
        int gn = n0 + wc + ni * 16 + lrow;
        sc[ni] = scale[gn];
        sh[ni] = shift[gn];
    }
#pragma unroll
    for (int mi = 0; mi < 4; ++mi) {
        int gm = m0 + wr + mi * 16 + (quad << 2);
#pragma unroll
        for (int ri = 0; ri < 4; ++ri) {
            size_t ro = (size_t)(gm + ri) * 256 + n0 + wc + lrow;
#pragma unroll
            for (int ni = 0; ni < 4; ++ni) {
                float v = acc[mi][ni][ri] * sc[ni] + sh[ni];
                v = fmaxf(v, 0.f);
                Out[ro + ni * 16] = f2bf(v);
            }
        }
    }
}

// ---------------- depthwise xcorr (4 ci per thread, uint2 loads) ----------------
__global__ __launch_bounds__(256) void xcorr(const u16* __restrict__ ss, const u16* __restrict__ kk,
                                             u16* __restrict__ f) {
    int bid = blockIdx.x;           // b*25 + y
    int b = bid / 25, y = bid - b * 25;
    int t = threadIdx.x;
    int cg = (t & 63) << 2;         // ci base, 4 per thread
    int xq = t >> 6;                // x phase
    float kv[25][4];
#pragma unroll
    for (int i = 0; i < 25; ++i) {
        uint2 kb = *(const uint2*)(kk + (size_t)(b * 25 + i) * 256 + cg);
        kv[i][0] = bf2f((u16)(kb.x & 0xffff));
        kv[i][1] = bf2f((u16)(kb.x >> 16));
        kv[i][2] = bf2f((u16)(kb.y & 0xffff));
        kv[i][3] = bf2f((u16)(kb.y >> 16));
    }
    const u16* sbase = ss + (size_t)(b * 29 + y) * 29 * 256 + cg;
    u16* fbase = f + (size_t)(b * 25 + y) * 25 * 256 + cg;
    for (int x = xq; x < 25; x += 4) {
        float a0 = 0.f, a1 = 0.f, a2 = 0.f, a3 = 0.f;
#pragma unroll
        for (int r = 0; r < 5; ++r)
#pragma unroll
            for (int c = 0; c < 5; ++c) {
                uint2 sv = *(const uint2*)(sbase + (r * 29 + x + c) * 256);
                a0 += bf2f((u16)(sv.x & 0xffff)) * kv[r * 5 + c][0];
                a1 += bf2f((u16)(sv.x >> 16))    * kv[r * 5 + c][1];
                a2 += bf2f((u16)(sv.y & 0xffff)) * kv[r * 5 + c][2];
                a3 += bf2f((u16)(sv.y >> 16))    * kv[r * 5 + c][3];
            }
        uint2 o;
        o.x = (u32)f2bf(a0) | ((u32)f2bf(a1) << 16);
        o.y = (u32)f2bf(a2) | ((u32)f2bf(a3) << 16);
        *(uint2*)(fbase + x * 256) = o;
    }
}

// ---------------- final 1x1 conv (256->20) + bias, NCHW fp32 out ----------------
__global__ __launch_bounds__(256) void head(const u16* __restrict__ h, const float* __restrict__ w2,
                                            const float* __restrict__ b2, float* __restrict__ out) {
    __shared__ u16   hl[25 * 264];
    __shared__ float wl[20 * 257];
    int bid = blockIdx.x;            // b*25 + y
    int b = bid / 25, y = bid - b * 25;
    int t = threadIdx.x;
    const u16* hrow = h + (size_t)(b * 25 + y) * 25 * 256;
    for (int i = t; i < 6400; i += 256) {
        int x = i >> 8, c = i & 255;
        hl[x * 264 + c] = hrow[i];
    }
    for (int i = t; i < 5120; i += 256) {
        int co = i >> 8, c = i & 255;
        wl[co * 257 + c] = w2[i];
    }
    __syncthreads();
    for (int o = t; o < 500; o += 256) {
        int x = o / 20, co = o - x * 20;
        float acc = b2[co];
        const u16* hp = &hl[x * 264];
        const float* wp = &wl[co * 257];
        for (int k = 0; k < 256; ++k) acc += bf2f(hp[k]) * wp[k];
        out[(size_t)((b * 20 + co) * 25 + y) * 25 + x] = acc;
    }
}

// ---------------- workspace layout ----------------
#define OFF_SIN  0ull
#define SZ_SIN   62980096ull      // 128*31*31*256*2
#define OFF_KIN  (OFF_SIN + SZ_SIN)
#define SZ_KIN   3211264ull       // 128*7*7*256*2
#define OFF_WKP  (OFF_KIN + SZ_KIN)
#define SZ_WKP   1179648ull
#define OFF_WSP  (OFF_WKP + SZ_WKP)
#define SZ_WSP   1179648ull
#define OFF_WH1P (OFF_WSP + SZ_WSP)
#define SZ_WH1P  131072ull
#define OFF_PAR  (OFF_WH1P + SZ_WH1P)
#define SZ_PAR   8192ull
#define OFF_KK   (OFF_PAR + SZ_PAR)
#define SZ_KK    1638400ull       // 128*25*256*2
#define OFF_SS   (OFF_KK + SZ_KK)
#define SZ_SS    55115776ull      // 128*29*29*256*2
#define OFF_F    OFF_SIN          // reuse: sin dead after search conv
#define OFF_H    OFF_SS           // reuse: ss dead after xcorr

extern "C" void kernel_launch(void* const* d_in, const int* in_sizes, int n_in,
                              void* d_out, int out_size, void* d_ws, size_t ws_size,
                              hipStream_t stream) {
    const float* kin  = (const float*)d_in[0];
    const float* sin_ = (const float*)d_in[1];
    const float* wk   = (const float*)d_in[2];
    const float* gk   = (const float*)d_in[3];
    const float* bk   = (const float*)d_in[4];
    const float* mk   = (const float*)d_in[5];
    const float* vk   = (const float*)d_in[6];
    const float* wsw  = (const float*)d_in[7];
    const float* gs   = (const float*)d_in[8];
    const float* bs   = (const float*)d_in[9];
    const float* ms   = (const float*)d_in[10];
    const float* vs   = (const float*)d_in[11];
    const float* wh1  = (const float*)d_in[12];
    const float* gh   = (const float*)d_in[13];
    const float* bh   = (const float*)d_in[14];
    const float* mh   = (const float*)d_in[15];
    const float* vh   = (const float*)d_in[16];
    const float* wh2  = (const float*)d_in[17];
    const float* bh2  = (const float*)d_in[18];
    float* out = (float*)d_out;

    char* w = (char*)d_ws;
    u16*   SIN  = (u16*)(w + OFF_SIN);
    u16*   KIN  = (u16*)(w + OFF_KIN);
    u16*   WKP  = (u16*)(w + OFF_WKP);
    u16*   WSP  = (u16*)(w + OFF_WSP);
    u16*   WH1P = (u16*)(w + OFF_WH1P);
    float* PAR  = (float*)(w + OFF_PAR);
    u16*   KK   = (u16*)(w + OFF_KK);
    u16*   SS   = (u16*)(w + OFF_SS);
    u16*   F    = (u16*)(w + OFF_F);
    u16*   H    = (u16*)(w + OFF_H);

    prep<<<4865, 256, 0, stream>>>(wk, wsw, wh1, gk, bk, mk, vk, gs, bs, ms, vs,
                                   gh, bh, mh, vh, WKP, WSP, WH1P, PAR);
    nchw2nhwc_t<<<1024 + 15872, 256, 0, stream>>>(kin, sin_, KIN, SIN);

    // kernel branch conv3x3+bn+relu: M=3200 (25 m-blocks)
    conv_gemm<0><<<50, 256, 0, stream>>>(KIN, WKP, PAR + 0, PAR + 256, KK,
                                         25, 5, 7, 12544, 3, 9, 25);
    // search branch conv3x3+bn+relu: M=107648 (841 m-blocks)
    conv_gemm<1><<<1682, 256, 0, stream>>>(SIN, WSP, PAR + 512, PAR + 768, SS,
                                           841, 29, 31, 246016, 3, 9, 841);
    // depthwise xcorr
    xcorr<<<3200, 256, 0, stream>>>(SS, KK, F);
    // 1x1 conv + bn + relu: M=80000 (625 m-blocks)
    conv_gemm<2><<<1250, 256, 0, stream>>>(F, WH1P, PAR + 1024, PAR + 1280, H,
                                           625, 25, 25, 160000, 1, 1, 625);
    // head
    head<<<3200, 256, 0, stream>>>(H, wh2, bh2, out);

    (void)in_sizes; (void)n_in; (void)out_size; (void)ws_size;
}

// Round 7
// 677.374 us; speedup vs baseline: 1.4994x; 1.4994x over previous
//
#include <hip/hip_runtime.h>

typedef __bf16 bf16x8 __attribute__((ext_vector_type(8)));
typedef float floatx4 __attribute__((ext_vector_type(4)));
typedef unsigned short u16;
typedef unsigned int u32;

__device__ __forceinline__ u16 f2bf(float f) {
    union { float f; unsigned int u; } q; q.f = f;
    unsigned int r = q.u + 0x7FFFu + ((q.u >> 16) & 1u);
    return (u16)(r >> 16);
}
__device__ __forceinline__ float bf2f(u16 b) {
    union { unsigned int u; float f; } q; q.u = ((unsigned int)b) << 16;
    return q.f;
}

// async 16B global -> LDS DMA. offset MUST stay 0: the imm offset shifts the LDS write
// address (M0+offset+lane*16), not the global address (round-3/4 NaN lesson).
__device__ __forceinline__ void gl2lds16(const u16* g, u16* l) {
    __builtin_amdgcn_global_load_lds((const __attribute__((address_space(1))) u32*)g,
                                     (__attribute__((address_space(3))) u32*)l, 16, 0, 0);
}

// ---------------- fused prep: pack both 3x3 weights, cast wh1, bn params ----------------
__global__ __launch_bounds__(256) void prep(
    const float* __restrict__ wk, const float* __restrict__ wsw, const float* __restrict__ wh1,
    const float* __restrict__ gk, const float* __restrict__ bk,
    const float* __restrict__ mk, const float* __restrict__ vk,
    const float* __restrict__ gs, const float* __restrict__ bs,
    const float* __restrict__ ms, const float* __restrict__ vs,
    const float* __restrict__ gh, const float* __restrict__ bh,
    const float* __restrict__ mh, const float* __restrict__ vh,
    u16* __restrict__ WKP, u16* __restrict__ WSP, u16* __restrict__ WH1P,
    float* __restrict__ par)
{
    int blk = blockIdx.x;
    int t = threadIdx.x;
    if (blk < 4608) {  // pack3x3: OIHW fp32 -> [o][(r*3+c)*256+ci] bf16
        const float* w = (blk < 2304) ? wk : wsw;
        u16* o_ = (blk < 2304) ? WKP : WSP;
        int tid = ((blk < 2304) ? blk : blk - 2304) * 256 + t;
        int o  = tid / 2304;
        int k  = tid - o * 2304;
        int rc = k >> 8;
        int ci = k & 255;
        o_[tid] = f2bf(w[o * 2304 + ci * 9 + rc]);
    } else if (blk < 4864) {  // cast wh1
        int tid = (blk - 4608) * 256 + t;
        WH1P[tid] = f2bf(wh1[tid]);
    } else {  // bn params
        int i = t;
        float s;
        s = gk[i] * rsqrtf(vk[i] + 1e-5f); par[0*256+i] = s; par[1*256+i] = bk[i] - mk[i]*s;
        s = gs[i] * rsqrtf(vs[i] + 1e-5f); par[2*256+i] = s; par[3*256+i] = bs[i] - ms[i]*s;
        s = gh[i] * rsqrtf(vh[i] + 1e-5f); par[4*256+i] = s; par[5*256+i] = bh[i] - mh[i]*s;
    }
}

// ---------------- NCHW fp32 -> NHWC bf16 (both inputs, one launch) ----------------
__global__ __launch_bounds__(256) void nchw2nhwc_t(const float* __restrict__ kin, const float* __restrict__ sin_,
                                                   u16* __restrict__ KIN, u16* __restrict__ SIN) {
    __shared__ float tile[64][33];
    int bid = blockIdx.x;
    const float* in; u16* out; int HW, sptiles;
    if (bid < 1024) { in = kin;  out = KIN; HW = 49;  sptiles = 2;  }
    else            { bid -= 1024; in = sin_; out = SIN; HW = 961; sptiles = 31; }
    int st  = bid % sptiles;
    int tmp = bid / sptiles;
    int ct  = tmp & 3;
    int b   = tmp >> 2;
    int sp0 = st * 32, ci0 = ct * 64;
    int t = threadIdx.x;
    int j = t & 31, i8 = t >> 5;
    const float* ip = in + ((size_t)b * 256 + ci0 + i8) * HW + sp0 + j;
#pragma unroll
    for (int k = 0; k < 8; ++k) {
        if (sp0 + j < HW) tile[i8 + k * 8][j] = ip[(size_t)(k * 8) * HW];
    }
    __syncthreads();
    int cl = t & 63, s4 = t >> 6;
#pragma unroll
    for (int k = 0; k < 8; ++k) {
        int spl = s4 + k * 4;
        int sp  = sp0 + spl;
        if (sp < HW) out[((size_t)b * HW + sp) * 256 + ci0 + cl] = f2bf(tile[cl][spl]);
    }
}

// ---------------- conv as implicit GEMM: 128x256 tile, 1-barrier pipelined dbuf ----------------
// Full N=256 per block; 4 waves in 2x2, each wave 64x128 (acc[4][8], 32 MFMA/chunk).
// Per chunk: waitcnt(0)+barrier -> 6 DMA for NEXT chunk (other parity) -> 12 ds_read_b128 +
// 32 MFMA of current parity. Distance-1 prefetch now has ~300+ cyc of compute to hide L2
// latency (the round-5 16-MFMA chunk had only ~80 cyc — why it was neutral).
#define CONV_CHUNK(C8)                                                          \
  {                                                                             \
    constexpr int pc = (C8) & 1;                                                \
    constexpr int pn = ((C8) + 1) & 1;                                          \
    __builtin_amdgcn_s_waitcnt(0);                                              \
    __syncthreads();                                                            \
    if ((C8) < 7) {                                                             \
      gl2lds16(ap0 + ((C8)+1)*32, Alds + pn*4096 + wv512);                      \
      gl2lds16(ap1 + ((C8)+1)*32, Alds + pn*4096 + 2048 + wv512);               \
      gl2lds16(wb0 + ((C8)+1)*32, Blds + pn*8192 + wv512);                      \
      gl2lds16(wb1 + ((C8)+1)*32, Blds + pn*8192 + 2048 + wv512);               \
      gl2lds16(wb2 + ((C8)+1)*32, Blds + pn*8192 + 4096 + wv512);               \
      gl2lds16(wb3 + ((C8)+1)*32, Blds + pn*8192 + 6144 + wv512);               \
    } else if (pf7) {                                                           \
      gl2lds16(an0, Alds + pn*4096 + wv512);                                    \
      gl2lds16(an1, Alds + pn*4096 + 2048 + wv512);                             \
      gl2lds16(wb0 + 256, Blds + pn*8192 + wv512);                              \
      gl2lds16(wb1 + 256, Blds + pn*8192 + 2048 + wv512);                       \
      gl2lds16(wb2 + 256, Blds + pn*8192 + 4096 + wv512);                       \
      gl2lds16(wb3 + 256, Blds + pn*8192 + 6144 + wv512);                       \
    }                                                                           \
    bf16x8 af[4], bfr[8];                                                       \
    _Pragma("unroll")                                                           \
    for (int mi = 0; mi < 4; ++mi)                                              \
      af[mi] = *(const bf16x8*)&Alds[pc*4096 + (wr + mi*16 + lrow)*32 + pos];   \
    _Pragma("unroll")                                                           \
    for (int ni = 0; ni < 8; ++ni)                                              \
      bfr[ni] = *(const bf16x8*)&Blds[pc*8192 + (wc + ni*16 + lrow)*32 + pos];  \
    _Pragma("unroll")                                                           \
    for (int mi = 0; mi < 4; ++mi)                                              \
      _Pragma("unroll")                                                         \
      for (int ni = 0; ni < 8; ++ni)                                            \
        acc[mi][ni] = __builtin_amdgcn_mfma_f32_16x16x32_bf16(af[mi], bfr[ni], acc[mi][ni], 0, 0, 0); \
  }

template<int TAG>
__global__ __launch_bounds__(256, 2) void conv_gemm(
    const u16* __restrict__ Ain, const u16* __restrict__ Wpk,
    const float* __restrict__ scale, const float* __restrict__ shift,
    u16* __restrict__ Out,
    int OHW, int OW, int IW, int bstride, int KW, int nrc, int mblocks)
{
    __shared__ u16 Alds[8192];    // 2 parities x 128x32 (8KB each)
    __shared__ u16 Blds[16384];   // 2 parities x 256x32 (16KB each)

    // XCD-contiguous remap over m-blocks
    const int tot = mblocks;
    const int grp = (tot >> 3) << 3;
    const int lid = blockIdx.x;
    const int nid = (lid < grp) ? ((lid & 7) * (grp >> 3) + (lid >> 3)) : lid;
    const int m0 = nid * 128;

    const int t     = threadIdx.x;
    const int wave  = t >> 6;
    const int lane  = t & 63;
    const int quad  = lane >> 4;
    const int lrow  = lane & 15;
    const int wv512 = wave * 512;

    // staging slot: thread t -> row t>>2, swizzled k-chunk (t&3)^((t>>3)&3) applied on the
    // GLOBAL pointer; rows t>>2 and (t>>2)+64/128/192 share the same koff (bit 8/9 don't
    // touch bits 0-4 of the slot index).
    const int koff = (((t & 3) ^ ((t >> 3) & 3)) << 3);
    const int r0 = t >> 2;
    int m_a0 = m0 + r0;
    int b0 = m_a0 / OHW; int rem0 = m_a0 - b0 * OHW; int y0 = rem0 / OW; int x0 = rem0 - y0 * OW;
    int m_a1 = m_a0 + 64;
    int b1 = m_a1 / OHW; int rem1 = m_a1 - b1 * OHW; int y1 = rem1 / OW; int x1 = rem1 - y1 * OW;
    const u16* ag0 = Ain + (size_t)b0 * bstride + (size_t)(y0 * IW + x0) * 256 + koff;
    const u16* ag1 = Ain + (size_t)b1 * bstride + (size_t)(y1 * IW + x1) * 256 + koff;
    const int Ktot = nrc << 8;
    const u16* wb0 = Wpk + (size_t)r0 * Ktot + koff;           // B rows r0, +64, +128, +192
    const u16* wb1 = wb0 + (size_t)64  * Ktot;
    const u16* wb2 = wb0 + (size_t)128 * Ktot;
    const u16* wb3 = wb0 + (size_t)192 * Ktot;

    floatx4 zero = {0.f, 0.f, 0.f, 0.f};
    floatx4 acc[4][8];
#pragma unroll
    for (int i = 0; i < 4; ++i)
#pragma unroll
        for (int j = 0; j < 8; ++j) acc[i][j] = zero;

    const int wr  = (wave >> 1) << 6;    // 2x2 wave grid: 64 rows x 128 cols each
    const int wc  = (wave & 1) << 7;
    const int pos = ((quad ^ ((lrow >> 1) & 3)) << 3);   // frag-read chunk select (matches store swizzle)

    // prologue: DMA chunk 0 (tap 0) into parity 0
    const u16* ap0 = ag0;
    const u16* ap1 = ag1;
    gl2lds16(ap0, Alds + wv512);
    gl2lds16(ap1, Alds + 2048 + wv512);
    gl2lds16(wb0, Blds + wv512);
    gl2lds16(wb1, Blds + 2048 + wv512);
    gl2lds16(wb2, Blds + 4096 + wv512);
    gl2lds16(wb3, Blds + 6144 + wv512);

    for (int rc = 1; rc <= nrc; ++rc) {
        const bool pf7 = (rc < nrc);               // peel: no wrap prefetch on last tap
        int rr = rc / KW, cc2 = rc - rr * KW;      // NEXT tap
        int tapoff = (rr * IW + cc2) << 8;
        const u16* an0 = ag0 + tapoff;
        const u16* an1 = ag1 + tapoff;
        CONV_CHUNK(0) CONV_CHUNK(1) CONV_CHUNK(2) CONV_CHUNK(3)
        CONV_CHUNK(4) CONV_CHUNK(5) CONV_CHUNK(6) CONV_CHUNK(7)
        ap0 = an0; ap1 = an1;
        wb0 += 256; wb1 += 256; wb2 += 256; wb3 += 256;
    }

    float sc[8], sh[8];
#pragma unroll
    for (int ni = 0; ni < 8; ++ni) {
        int gn = wc + ni * 16 + lrow;
        sc[ni] = scale[gn];
        sh[ni] = shift[gn];
    }
#pragma unroll
    for (int mi = 0; mi < 4; ++mi) {
        int gm = m0 + wr + mi * 16 + (quad << 2);
#pragma unroll
        for (int ri = 0; ri < 4; ++ri) {
            size_t ro = (size_t)(gm + ri) * 256 + wc + lrow;
#pragma unroll
            for (int ni = 0; ni < 8; ++ni) {
                float v = acc[mi][ni][ri] * sc[ni] + sh[ni];
                v = fmaxf(v, 0.f);
                Out[ro + ni * 16] = f2bf(v);
            }
        }
    }
}

// ---------------- depthwise xcorr (4 ci per thread, uint2 loads) ----------------
__global__ __launch_bounds__(256) void xcorr(const u16* __restrict__ ss, const u16* __restrict__ kk,
                                             u16* __restrict__ f) {
    int bid = blockIdx.x;           // b*25 + y
    int b = bid / 25, y = bid - b * 25;
    int t = threadIdx.x;
    int cg = (t & 63) << 2;         // ci base, 4 per thread
    int xq = t >> 6;                // x phase
    float kv[25][4];
#pragma unroll
    for (int i = 0; i < 25; ++i) {
        uint2 kb = *(const uint2*)(kk + (size_t)(b * 25 + i) * 256 + cg);
        kv[i][0] = bf2f((u16)(kb.x & 0xffff));
        kv[i][1] = bf2f((u16)(kb.x >> 16));
        kv[i][2] = bf2f((u16)(kb.y & 0xffff));
        kv[i][3] = bf2f((u16)(kb.y >> 16));
    }
    const u16* sbase = ss + (size_t)(b * 29 + y) * 29 * 256 + cg;
    u16* fbase = f + (size_t)(b * 25 + y) * 25 * 256 + cg;
    for (int x = xq; x < 25; x += 4) {
        float a0 = 0.f, a1 = 0.f, a2 = 0.f, a3 = 0.f;
#pragma unroll
        for (int r = 0; r < 5; ++r)
#pragma unroll
            for (int c = 0; c < 5; ++c) {
                uint2 sv = *(const uint2*)(sbase + (r * 29 + x + c) * 256);
                a0 += bf2f((u16)(sv.x & 0xffff)) * kv[r * 5 + c][0];
                a1 += bf2f((u16)(sv.x >> 16))    * kv[r * 5 + c][1];
                a2 += bf2f((u16)(sv.y & 0xffff)) * kv[r * 5 + c][2];
                a3 += bf2f((u16)(sv.y >> 16))    * kv[r * 5 + c][3];
            }
        uint2 o;
        o.x = (u32)f2bf(a0) | ((u32)f2bf(a1) << 16);
        o.y = (u32)f2bf(a2) | ((u32)f2bf(a3) << 16);
        *(uint2*)(fbase + x * 256) = o;
    }
}

// ---------------- final 1x1 conv (256->20) + bias, NCHW fp32 out ----------------
__global__ __launch_bounds__(256) void head(const u16* __restrict__ h, const float* __restrict__ w2,
                                            const float* __restrict__ b2, float* __restrict__ out) {
    __shared__ u16   hl[25 * 264];
    __shared__ float wl[20 * 257];
    int bid = blockIdx.x;            // b*25 + y
    int b = bid / 25, y = bid - b * 25;
    int t = threadIdx.x;
    const u16* hrow = h + (size_t)(b * 25 + y) * 25 * 256;
    for (int i = t; i < 6400; i += 256) {
        int x = i >> 8, c = i & 255;
        hl[x * 264 + c] = hrow[i];
    }
    for (int i = t; i < 5120; i += 256) {
        int co = i >> 8, c = i & 255;
        wl[co * 257 + c] = w2[i];
    }
    __syncthreads();
    for (int o = t; o < 500; o += 256) {
        int x = o / 20, co = o - x * 20;
        float acc = b2[co];
        const u16* hp = &hl[x * 264];
        const float* wp = &wl[co * 257];
        for (int k = 0; k < 256; ++k) acc += bf2f(hp[k]) * wp[k];
        out[(size_t)((b * 20 + co) * 25 + y) * 25 + x] = acc;
    }
}

// ---------------- workspace layout ----------------
#define OFF_SIN  0ull
#define SZ_SIN   62980096ull      // 128*31*31*256*2
#define OFF_KIN  (OFF_SIN + SZ_SIN)
#define SZ_KIN   3211264ull       // 128*7*7*256*2
#define OFF_WKP  (OFF_KIN + SZ_KIN)
#define SZ_WKP   1179648ull
#define OFF_WSP  (OFF_WKP + SZ_WKP)
#define SZ_WSP   1179648ull
#define OFF_WH1P (OFF_WSP + SZ_WSP)
#define SZ_WH1P  131072ull
#define OFF_PAR  (OFF_WH1P + SZ_WH1P)
#define SZ_PAR   8192ull
#define OFF_KK   (OFF_PAR + SZ_PAR)
#define SZ_KK    1638400ull       // 128*25*256*2
#define OFF_SS   (OFF_KK + SZ_KK)
#define SZ_SS    55115776ull      // 128*29*29*256*2
#define OFF_F    OFF_SIN          // reuse: sin dead after search conv
#define OFF_H    OFF_SS           // reuse: ss dead after xcorr

extern "C" void kernel_launch(void* const* d_in, const int* in_sizes, int n_in,
                              void* d_out, int out_size, void* d_ws, size_t ws_size,
                              hipStream_t stream) {
    const float* kin  = (const float*)d_in[0];
    const float* sin_ = (const float*)d_in[1];
    const float* wk   = (const float*)d_in[2];
    const float* gk   = (const float*)d_in[3];
    const float* bk   = (const float*)d_in[4];
    const float* mk   = (const float*)d_in[5];
    const float* vk   = (const float*)d_in[6];
    const float* wsw  = (const float*)d_in[7];
    const float* gs   = (const float*)d_in[8];
    const float* bs   = (const float*)d_in[9];
    const float* ms   = (const float*)d_in[10];
    const float* vs   = (const float*)d_in[11];
    const float* wh1  = (const float*)d_in[12];
    const float* gh   = (const float*)d_in[13];
    const float* bh   = (const float*)d_in[14];
    const float* mh   = (const float*)d_in[15];
    const float* vh   = (const float*)d_in[16];
    const float* wh2  = (const float*)d_in[17];
    const float* bh2  = (const float*)d_in[18];
    float* out = (float*)d_out;

    char* w = (char*)d_ws;
    u16*   SIN  = (u16*)(w + OFF_SIN);
    u16*   KIN  = (u16*)(w + OFF_KIN);
    u16*   WKP  = (u16*)(w + OFF_WKP);
    u16*   WSP  = (u16*)(w + OFF_WSP);
    u16*   WH1P = (u16*)(w + OFF_WH1P);
    float* PAR  = (float*)(w + OFF_PAR);
    u16*   KK   = (u16*)(w + OFF_KK);
    u16*   SS   = (u16*)(w + OFF_SS);
    u16*   F    = (u16*)(w + OFF_F);
    u16*   H    = (u16*)(w + OFF_H);

    prep<<<4865, 256, 0, stream>>>(wk, wsw, wh1, gk, bk, mk, vk, gs, bs, ms, vs,
                                   gh, bh, mh, vh, WKP, WSP, WH1P, PAR);
    nchw2nhwc_t<<<1024 + 15872, 256, 0, stream>>>(kin, sin_, KIN, SIN);

    // kernel branch conv3x3+bn+relu: M=3200 (25 m-blocks, full N=256)
    conv_gemm<0><<<25, 256, 0, stream>>>(KIN, WKP, PAR + 0, PAR + 256, KK,
                                         25, 5, 7, 12544, 3, 9, 25);
    // search branch conv3x3+bn+relu: M=107648 (841 m-blocks)
    conv_gemm<1><<<841, 256, 0, stream>>>(SIN, WSP, PAR + 512, PAR + 768, SS,
                                          841, 29, 31, 246016, 3, 9, 841);
    // depthwise xcorr
    xcorr<<<3200, 256, 0, stream>>>(SS, KK, F);
    // 1x1 conv + bn + relu: M=80000 (625 m-blocks)
    conv_gemm<2><<<625, 256, 0, stream>>>(F, WH1P, PAR + 1024, PAR + 1280, H,
                                          625, 25, 25, 160000, 1, 1, 625);
    // head
    head<<<3200, 256, 0, stream>>>(H, wh2, bh2, out);

    (void)in_sizes; (void)n_in; (void)out_size; (void)ws_size;
}